// Round 2
// 854.477 us; speedup vs baseline: 1.1475x; 1.1475x over previous
//
#include <hip/hip_runtime.h>
#include <math.h>

// ---------------- types ----------------
typedef __bf16 bf16x8 __attribute__((ext_vector_type(8)));
typedef float  floatx4 __attribute__((ext_vector_type(4)));

__device__ inline float bf_lo(unsigned u){ return __uint_as_float(u << 16); }
__device__ inline float bf_hi(unsigned u){ return __uint_as_float(u & 0xffff0000u); }
__device__ inline unsigned short f2bf_u(float f){
    unsigned u = __float_as_uint(f);
    return (unsigned short)((u + 0x7fffu + ((u >> 16) & 1u)) >> 16);   // RNE
}
__device__ inline unsigned pack2(float a, float b){
    return (unsigned)f2bf_u(a) | ((unsigned)f2bf_u(b) << 16);
}
__device__ inline float gelu_f(float v){
    return 0.5f * v * (1.f + erff(v * 0.70710678118654752f));
}
__device__ inline void gload_lds16(const void* g, void* l){
    __builtin_amdgcn_global_load_lds(
        (const __attribute__((address_space(1))) unsigned int*)g,
        (__attribute__((address_space(3))) unsigned int*)l, 16, 0, 0);
}

// ---------------- utility ----------------
__global__ void zero_k(int* __restrict__ p, int n){
    int i = blockIdx.x * 256 + threadIdx.x;
    if (i < n) p[i] = 0;
}

__global__ void xcast_k(const float* __restrict__ x, unsigned short* __restrict__ xb, long n8){
    long i = (long)blockIdx.x * 256 + threadIdx.x;
    if (i < n8){
        const float4* p = (const float4*)(x + i * 8);
        float4 a = p[0], b = p[1];
        uint4 o;
        o.x = pack2(a.x, a.y); o.y = pack2(a.z, a.w);
        o.z = pack2(b.x, b.y); o.w = pack2(b.z, b.w);
        *(uint4*)(xb + i * 8) = o;
    }
}

// Wt[n*ostride + ooffs + k] = W[k][n], bf16
__global__ void wprep_k(const float* __restrict__ W, unsigned short* __restrict__ Wt,
                        int K, int Ncols, int ostride, int ooffs){
    int idx = blockIdx.x * 256 + threadIdx.x;
    if (idx < K * Ncols){
        int k = idx / Ncols, n = idx - k * Ncols;
        Wt[(size_t)n * ostride + ooffs + k] = f2bf_u(W[idx]);
    }
}

// ---------------- bucketed CSR build ----------------
// Buckets of RB=512 consecutive dst nodes (bucket = dst >> 9). nbuk <= 256.
// Counters in bcnt/bcur are padded to one per 64B line (stride 16 ints).

#define RBSH 9
#define RB   512
#define PCH  8192   // edges per bpart block

// global bucket histogram, LDS-aggregated
__global__ __launch_bounds__(256)
void bhist_k(const int* __restrict__ dst, int* __restrict__ bcnt, int E){
    __shared__ int h[256];
    for (int i = threadIdx.x; i < 256; i += 256) h[i] = 0;
    __syncthreads();
    for (long i = (long)blockIdx.x * 256 + threadIdx.x; i < E; i += (long)gridDim.x * 256)
        atomicAdd(&h[dst[i] >> RBSH], 1);
    __syncthreads();
    int v = h[threadIdx.x];
    if (v) atomicAdd(&bcnt[threadIdx.x * 16], v);
}

// exclusive scan over nbuk bucket counts; init padded cursors
__global__ void bscan_k(const int* __restrict__ bcnt, int* __restrict__ bbase,
                        int* __restrict__ bcur, int nbuk, int E){
    __shared__ int s[256];
    const int t = threadIdx.x;
    int v = (t < nbuk) ? bcnt[t * 16] : 0;
    s[t] = v; __syncthreads();
    for (int d = 1; d < 256; d <<= 1){
        int tt = (t >= d) ? s[t - d] : 0;
        __syncthreads();
        s[t] += tt;
        __syncthreads();
    }
    int excl = s[t] - v;
    if (t < nbuk){ bbase[t] = excl; bcur[t * 16] = excl; }
    if (t == 0) bbase[nbuk] = E;
}

// partition edges into bucket-grouped (src,dst) pairs.
// Per-block LDS hist + scan + one reservation atomic per (block,bucket);
// a block's pairs for one bucket land contiguously (~336B runs).
__global__ __launch_bounds__(512)
void bpart_k(const int* __restrict__ src, const int* __restrict__ dst,
             int* __restrict__ bcur, int2* __restrict__ pairs, int E){
    __shared__ int h[256];
    __shared__ int s[256];
    __shared__ int cur[256];
    const int t = threadIdx.x;
    const int base = blockIdx.x * PCH;
    const int cnt = min(PCH, E - base);
    if (t < 256) h[t] = 0;
    __syncthreads();
    for (int i = t; i < cnt; i += 512)
        atomicAdd(&h[dst[base + i] >> RBSH], 1);
    __syncthreads();
    if (t < 256) s[t] = h[t];
    __syncthreads();
    for (int d = 1; d < 256; d <<= 1){
        int tt = 0;
        if (t < 256 && t >= d) tt = s[t - d];
        __syncthreads();
        if (t < 256) s[t] += tt;
        __syncthreads();
    }
    if (t < 256){
        int myc = h[t];
        int g = 0;
        if (myc) g = atomicAdd(&bcur[t * 16], myc);
        cur[t] = g;
    }
    __syncthreads();
    for (int i = t; i < cnt; i += 512){
        int d = dst[base + i];
        int b = d >> RBSH;
        int r = atomicAdd(&cur[b], 1);
        pairs[r] = make_int2(src[base + i], d);
    }
}

// per-bucket CSR finalize: offsets (coalesced) + esrc scatter within the
// bucket's own ~32KB region (L2-resident, full lines -> streamed writeback).
__global__ __launch_bounds__(1024)
void bbuild_k(const int2* __restrict__ pairs, const int* __restrict__ bbase,
              int* __restrict__ offsets, int* __restrict__ esrc, int N, int E){
    __shared__ int h[RB];
    __shared__ int s[RB];
    const int b = blockIdx.x;
    const int t = threadIdx.x;
    const int p0 = bbase[b], p1 = bbase[b + 1];
    if (t < RB) h[t] = 0;
    __syncthreads();
    for (int i = p0 + t; i < p1; i += 1024)
        atomicAdd(&h[pairs[i].y & (RB - 1)], 1);
    __syncthreads();
    int v = 0;
    if (t < RB){ v = h[t]; s[t] = v; }
    __syncthreads();
    for (int d = 1; d < RB; d <<= 1){
        int tt = 0;
        if (t < RB && t >= d) tt = s[t - d];
        __syncthreads();
        if (t < RB) s[t] += tt;
        __syncthreads();
    }
    if (t < RB){
        int node = (b << RBSH) + t;
        int excl = p0 + s[t] - v;
        if (node < N) offsets[node] = excl;
        h[t] = excl;                       // reuse hist as cursor
    }
    __syncthreads();
    for (int i = p0 + t; i < p1; i += 1024){
        int2 pr = pairs[i];
        int r = atomicAdd(&h[pr.y & (RB - 1)], 1);
        esrc[r] = pr.x;
    }
    if (b == 0 && t == 0) offsets[N] = E;
}

// ---------------- aggregation into AG[:,0:256]; hbn = AG+256, both row-stride 512 ----------------
__global__ __launch_bounds__(256)
void agg_k(const unsigned short* __restrict__ hbn, const int* __restrict__ offsets,
           const int* __restrict__ esrc, unsigned short* __restrict__ aggout, int N){
    const int lane = threadIdx.x & 63;
    const int node = blockIdx.x * 4 + (threadIdx.x >> 6);
    if (node >= N) return;
    const int off = offsets[node];
    const int end = offsets[node + 1];
    float a0 = 0.f, a1 = 0.f, a2 = 0.f, a3 = 0.f;
    for (int c = off; c < end; c += 64){
        const int e = c + lane;
        int sl = (e < end) ? esrc[e] : 0;
        const int cnt = min(64, end - c);
        for (int j = 0; j < cnt; ++j){
            const int s = __shfl(sl, j);
            const uint2 u = *(const uint2*)(hbn + (size_t)s * 512 + lane * 4);
            a0 += bf_lo(u.x); a1 += bf_hi(u.x);
            a2 += bf_lo(u.y); a3 += bf_hi(u.y);
        }
    }
    uint2 o; o.x = pack2(a0, a1); o.y = pack2(a2, a3);
    *(uint2*)(aggout + (size_t)node * 512 + lane * 4) = o;
}

// ---------------- GEMM v3 (m97 structure, swapped operands) ----------------
// C[M][NCOLS] = A[M][K](bf16) @ W, W given as Bt[n][k] bf16 row-stride K.
// Tile BM=128 x BN=64 x BK=64; 4 waves, wave w owns rows [w*32, w*32+32).
// Operand swap: A-operand = weight frag (m-index = out-col), B-operand = X frag
// (n-index = node row). D: col(lane&15)=node, row(q4*4+r)=out-col → lane holds 4
// consecutive out-cols of one node → 8B stores.
template<int K, bool GELU_OUT>
__global__ __launch_bounds__(256)
void gemm3_k(const unsigned short* __restrict__ A, const unsigned short* __restrict__ Bt,
             const float* __restrict__ bias, unsigned short* __restrict__ Cp,
             long M, int NCOLS){
    __shared__ unsigned short Xs[128 * 64];   // [row][k]
    __shared__ unsigned short Ws[64 * 64];    // [col][k]
    const int t    = threadIdx.x;
    const int lane = t & 63;
    const int w    = t >> 6;
    const int r16  = lane & 15;
    const int q4   = lane >> 4;
    const long mbase = (long)blockIdx.x * 128;
    const int  cb    = blockIdx.y * 64;

    floatx4 acc[4][2];
#pragma unroll
    for (int ai = 0; ai < 4; ++ai)
#pragma unroll
        for (int bi = 0; bi < 2; ++bi) acc[ai][bi] = (floatx4)0.f;

    // staging lane geometry: 16B per lane; row = 8 rows/wave-iter
    const int lrow = w * 8 + (lane >> 3);
    const int lk   = (lane & 7) * 8;
    const unsigned short* ga = A  + (size_t)(mbase + lrow) * K + lk;
    const unsigned short* gb = Bt + (size_t)(cb + lrow) * K + lk;
    unsigned short* lx = Xs + w * 512 + lane * 8;
    unsigned short* lw = Ws + w * 512 + lane * 8;

    for (int kt = 0; kt < K; kt += 64){
#pragma unroll
        for (int i = 0; i < 4; ++i)
            gload_lds16(ga + (size_t)i * 32 * K + kt, lx + i * 2048);
#pragma unroll
        for (int j = 0; j < 2; ++j)
            gload_lds16(gb + (size_t)j * 32 * K + kt, lw + j * 2048);
        asm volatile("s_waitcnt vmcnt(0)" ::: "memory");
        __syncthreads();
#pragma unroll
        for (int kc = 0; kc < 64; kc += 32){
            bf16x8 wf[4], xf[2];
#pragma unroll
            for (int ai = 0; ai < 4; ++ai)
                wf[ai] = *(const bf16x8*)(Ws + (ai * 16 + r16) * 64 + kc + q4 * 8);
#pragma unroll
            for (int bi = 0; bi < 2; ++bi)
                xf[bi] = *(const bf16x8*)(Xs + (w * 32 + bi * 16 + r16) * 64 + kc + q4 * 8);
#pragma unroll
            for (int ai = 0; ai < 4; ++ai)
#pragma unroll
                for (int bi = 0; bi < 2; ++bi)
                    acc[ai][bi] = __builtin_amdgcn_mfma_f32_16x16x32_bf16(
                        wf[ai], xf[bi], acc[ai][bi], 0, 0, 0);
        }
        __syncthreads();
    }

    // epilogue: bias (+gelu), 8B vector stores
    float4 bv[4];
#pragma unroll
    for (int ai = 0; ai < 4; ++ai)
        bv[ai] = *(const float4*)(bias + cb + ai * 16 + q4 * 4);
#pragma unroll
    for (int bi = 0; bi < 2; ++bi){
        long node = mbase + w * 32 + bi * 16 + r16;
        if (node < M){
            unsigned short* cp = Cp + (size_t)node * NCOLS + cb;
#pragma unroll
            for (int ai = 0; ai < 4; ++ai){
                float v0 = acc[ai][bi][0] + bv[ai].x;
                float v1 = acc[ai][bi][1] + bv[ai].y;
                float v2 = acc[ai][bi][2] + bv[ai].z;
                float v3 = acc[ai][bi][3] + bv[ai].w;
                if constexpr (GELU_OUT){
                    v0 = gelu_f(v0); v1 = gelu_f(v1); v2 = gelu_f(v2); v3 = gelu_f(v3);
                }
                uint2 o; o.x = pack2(v0, v1); o.y = pack2(v2, v3);
                *(uint2*)(cp + ai * 16 + q4 * 4) = o;
            }
        }
    }
}

// ---------------- column stats: gsum[c] += sum rows, gsq[c] += sum rows^2 ----------------
template<int NCOLS>
__global__ void colstats_k(const unsigned short* __restrict__ in,
                           float* __restrict__ gsum, float* __restrict__ gsq, long nrows){
    constexpr int TPR  = NCOLS / 8;
    constexpr int BDIM = (NCOLS == 192) ? 192 : 256;
    constexpr int ROWS = BDIM / TPR;
    __shared__ float sS[ROWS * NCOLS], sQ[ROWS * NCOLS];
    const int t  = threadIdx.x;
    const int c8 = (t % TPR) * 8;
    const int r  = t / TPR;
    float s[8], q[8];
#pragma unroll
    for (int j = 0; j < 8; ++j){ s[j] = 0.f; q[j] = 0.f; }
    for (long row = (long)blockIdx.x * ROWS + r; row < nrows; row += (long)gridDim.x * ROWS){
        uint4 u = *(const uint4*)(in + row * NCOLS + c8);
        float v[8];
        v[0] = bf_lo(u.x); v[1] = bf_hi(u.x); v[2] = bf_lo(u.y); v[3] = bf_hi(u.y);
        v[4] = bf_lo(u.z); v[5] = bf_hi(u.z); v[6] = bf_lo(u.w); v[7] = bf_hi(u.w);
#pragma unroll
        for (int j = 0; j < 8; ++j){ s[j] += v[j]; q[j] += v[j] * v[j]; }
    }
#pragma unroll
    for (int j = 0; j < 8; ++j){ sS[r * NCOLS + c8 + j] = s[j]; sQ[r * NCOLS + c8 + j] = q[j]; }
    __syncthreads();
    for (int c = t; c < NCOLS; c += BDIM){
        float as = 0.f, aq = 0.f;
#pragma unroll
        for (int rr = 0; rr < ROWS; ++rr){ as += sS[rr * NCOLS + c]; aq += sQ[rr * NCOLS + c]; }
        atomicAdd(&gsum[c], as);
        atomicAdd(&gsq[c],  aq);
    }
}

// ---------------- BN apply (+gelu, +residual, strided out, fp32/bf16 out) ----------------
template<int NCOLS, bool GELU_OUT, bool RES, bool RES_F32, bool OUT_F32>
__global__ __launch_bounds__(256)
void bn_apply_k(const unsigned short* __restrict__ in, void* __restrict__ outv,
                const void* __restrict__ resv,
                const float* __restrict__ gsum, const float* __restrict__ gsq,
                const float* __restrict__ gamma, const float* __restrict__ beta,
                long nrows, int ostride, int ooffs, float invN){
    __shared__ float s_scale[NCOLS], s_shift[NCOLS];
    for (int c = threadIdx.x; c < NCOLS; c += 256){
        float mean = gsum[c] * invN;
        float var  = gsq[c] * invN - mean * mean;
        float sc   = gamma[c] * rsqrtf(var + 1e-5f);
        s_scale[c] = sc;
        s_shift[c] = beta[c] - mean * sc;
    }
    __syncthreads();
    long i8 = ((long)blockIdx.x * 256 + threadIdx.x) * 8;
    if (i8 >= nrows * (long)NCOLS) return;
    long row  = i8 / NCOLS;
    int  col0 = (int)(i8 - row * NCOLS);
    uint4 u = *(const uint4*)(in + i8);
    float v[8];
    v[0] = bf_lo(u.x); v[1] = bf_hi(u.x); v[2] = bf_lo(u.y); v[3] = bf_hi(u.y);
    v[4] = bf_lo(u.z); v[5] = bf_hi(u.z); v[6] = bf_lo(u.w); v[7] = bf_hi(u.w);
#pragma unroll
    for (int j = 0; j < 8; ++j){
        v[j] = v[j] * s_scale[col0 + j] + s_shift[col0 + j];
        if constexpr (GELU_OUT) v[j] = gelu_f(v[j]);
    }
    if constexpr (RES){
        if constexpr (RES_F32){
            const float4* rp = (const float4*)((const float*)resv + i8);
            float4 r0 = rp[0], r1 = rp[1];
            v[0] += r0.x; v[1] += r0.y; v[2] += r0.z; v[3] += r0.w;
            v[4] += r1.x; v[5] += r1.y; v[6] += r1.z; v[7] += r1.w;
        } else {
            uint4 r = *(const uint4*)((const unsigned short*)resv + i8);
            v[0] += bf_lo(r.x); v[1] += bf_hi(r.x); v[2] += bf_lo(r.y); v[3] += bf_hi(r.y);
            v[4] += bf_lo(r.z); v[5] += bf_hi(r.z); v[6] += bf_lo(r.w); v[7] += bf_hi(r.w);
        }
    }
    long opos = row * ostride + ooffs + col0;
    if constexpr (OUT_F32){
        float4* op = (float4*)((float*)outv + opos);
        op[0] = make_float4(v[0], v[1], v[2], v[3]);
        op[1] = make_float4(v[4], v[5], v[6], v[7]);
    } else {
        uint4 o;
        o.x = pack2(v[0], v[1]); o.y = pack2(v[2], v[3]);
        o.z = pack2(v[4], v[5]); o.w = pack2(v[6], v[7]);
        *(uint4*)((unsigned short*)outv + opos) = o;
    }
}

// ---------------- host ----------------
extern "C" void kernel_launch(void* const* d_in, const int* in_sizes, int n_in,
                              void* d_out, int out_size, void* d_ws, size_t ws_size,
                              hipStream_t stream){
    const int C = 192, GH = 256, FH = 512;
    const float* x    = (const float*)d_in[0];
    const int*   ei   = (const int*)d_in[1];
    const float* Wg1  = (const float*)d_in[2];
    const float* bg1  = (const float*)d_in[3];
    const float* gg1  = (const float*)d_in[4];
    const float* beg1 = (const float*)d_in[5];
    const float* Wrel = (const float*)d_in[6];
    const float* brel = (const float*)d_in[7];
    const float* Wroot= (const float*)d_in[8];
    const float* Wg2  = (const float*)d_in[9];
    const float* bg2  = (const float*)d_in[10];
    const float* gg2  = (const float*)d_in[11];
    const float* beg2 = (const float*)d_in[12];
    const float* Wf1  = (const float*)d_in[13];
    const float* bf1  = (const float*)d_in[14];
    const float* gf1  = (const float*)d_in[15];
    const float* bef1 = (const float*)d_in[16];
    const float* Wf2  = (const float*)d_in[17];
    const float* bf2  = (const float*)d_in[18];
    const float* gf2  = (const float*)d_in[19];
    const float* bef2 = (const float*)d_in[20];

    const int N = in_sizes[0] / C;
    const int E = in_sizes[1] / 2;
    const int* e_src = ei;
    const int* e_dst = ei + E;

    // ---- workspace arena (~214 MB). Big A-source buffers placed BEFORE the
    // int buffers so gemm3's ≤130 KB staging over-read stays in-arena. ----
    char* wp = (char*)d_ws;
    auto carve = [&](size_t bytes) -> void* {
        void* p = (void*)wp; wp += (bytes + 255) & ~(size_t)255; return p;
    };
    unsigned short* wt_g1 = (unsigned short*)carve((size_t)GH * C * 2);     // [256][192]
    unsigned short* wt_rr = (unsigned short*)carve((size_t)GH * 512 * 2);   // [256][512] = [Wrel^T|Wroot^T]
    unsigned short* wt_g2 = (unsigned short*)carve((size_t)C * GH * 2);     // [192][256]
    unsigned short* wt_f1 = (unsigned short*)carve((size_t)FH * C * 2);     // [512][192]
    unsigned short* wt_f2 = (unsigned short*)carve((size_t)C * FH * 2);     // [192][512]
    float* stats = (float*)carve(2 * (size_t)(GH + C + FH + C) * 4);
    float* sum1 = stats;        float* sq1 = sum1 + GH;
    float* sum2 = sq1 + GH;     float* sq2 = sum2 + C;
    float* sum3 = sq2 + C;      float* sq3 = sum3 + FH;
    float* sum4 = sq3 + FH;     float* sq4 = sum4 + C;
    // buf0 [N,512]: pairs (CSR build, dies before h1) -> h1[N,256] -> g[N,256] -> f1/g2[N,512]
    unsigned short* buf0  = (unsigned short*)carve((size_t)N * 512 * 2);
    // bufAG [N,512]: x_bf[N,192] (dies at g1) -> AG=[agg|hbn] -> h2/x2[N,192]@0, h4[N,192]@N*192
    unsigned short* bufAG = (unsigned short*)carve((size_t)N * 512 * 2);
    int* offsets = (int*)carve((size_t)(N + 1) * 4);
    int* esrc    = (int*)carve((size_t)E * 4);
    int* bcnt    = (int*)carve((size_t)256 * 16 * 4);   // padded: 1 counter / 64B line
    int* bbase   = (int*)carve((size_t)257 * 4);
    int* bcur    = (int*)carve((size_t)256 * 16 * 4);   // padded
    unsigned short* x_bf = bufAG;                       // [N,192] overlay, dead before AG written
    int2* pairs = (int2*)buf0;                          // [E] overlay, dead before h1 written
    unsigned short* h1  = buf0;
    unsigned short* g   = buf0;
    unsigned short* f1  = buf0;                          // also g2 (in-place BN)
    unsigned short* AG  = bufAG;
    unsigned short* h2  = bufAG;                         // also x2 (in-place BN+res)
    unsigned short* h4  = bufAG + (size_t)N * C;
    (void)ws_size; (void)n_in; (void)out_size;

    const float invN = 1.0f / (float)N;
    const int GB = (N + 127) / 128;   // gemm3 grid.x
    const int nbuk = (N + RB - 1) >> RBSH;   // <=256 for N<=131072

    // weight prep
    wprep_k<<<(C * GH + 255) / 256, 256, 0, stream>>>(Wg1, wt_g1, C, GH, C, 0);
    wprep_k<<<(GH * GH + 255) / 256, 256, 0, stream>>>(Wrel, wt_rr, GH, GH, 512, 0);
    wprep_k<<<(GH * GH + 255) / 256, 256, 0, stream>>>(Wroot, wt_rr, GH, GH, 512, GH);
    wprep_k<<<(GH * C + 255) / 256, 256, 0, stream>>>(Wg2, wt_g2, GH, C, GH, 0);
    wprep_k<<<(C * FH + 255) / 256, 256, 0, stream>>>(Wf1, wt_f1, C, FH, C, 0);
    wprep_k<<<(FH * C + 255) / 256, 256, 0, stream>>>(Wf2, wt_f2, FH, C, FH, 0);

    const int nstats = 2 * (GH + C + FH + C);
    zero_k<<<(nstats + 255) / 256, 256, 0, stream>>>((int*)stats, nstats);
    zero_k<<<(256 * 16 + 255) / 256, 256, 0, stream>>>(bcnt, 256 * 16);

    // bucketed CSR build
    bhist_k<<<1024, 256, 0, stream>>>(e_dst, bcnt, E);
    bscan_k<<<1, 256, 0, stream>>>(bcnt, bbase, bcur, nbuk, E);
    bpart_k<<<(E + PCH - 1) / PCH, 512, 0, stream>>>(e_src, e_dst, bcur, pairs, E);
    bbuild_k<<<nbuk, 1024, 0, stream>>>(pairs, bbase, offsets, esrc, N, E);

    // x -> bf16 (for g1 GEMM A-input)
    xcast_k<<<(int)(((size_t)N * C / 8 + 255) / 256), 256, 0, stream>>>(x, x_bf, (long)N * C / 8);

    // ---- Grapher ----
    // h1 = x @ Wg1 + bg1
    gemm3_k<192, false><<<dim3(GB, GH / 64), 256, 0, stream>>>(x_bf, wt_g1, bg1, h1, N, GH);
    colstats_k<256><<<512, 256, 0, stream>>>(h1, sum1, sq1, N);
    // hbn = BN(h1) -> AG[:,256:512]   (x_bf dies here)
    bn_apply_k<256, false, false, false, false><<<(int)(((size_t)N * GH / 8 + 255) / 256), 256, 0, stream>>>(
        h1, AG, nullptr, sum1, sq1, gg1, beg1, N, 512, 256, invN);
    // agg -> AG[:,0:256]
    agg_k<<<(N + 3) / 4, 256, 0, stream>>>(AG + 256, offsets, esrc, AG, N);
    // g = gelu([agg|hbn] @ [Wrel;Wroot] + brel)
    gemm3_k<512, true><<<dim3(GB, GH / 64), 256, 0, stream>>>(AG, wt_rr, brel, g, N, GH);
    // h2 = g @ Wg2 + bg2
    gemm3_k<256, false><<<dim3(GB, C / 64), 256, 0, stream>>>(g, wt_g2, bg2, h2, N, C);
    colstats_k<192><<<512, 192, 0, stream>>>(h2, sum2, sq2, N);
    // x2 = BN(h2) + x   (in-place)
    bn_apply_k<192, false, true, true, false><<<(int)(((size_t)N * C / 8 + 255) / 256), 256, 0, stream>>>(
        h2, h2, x, sum2, sq2, gg2, beg2, N, 192, 0, invN);

    // ---- FFN ----
    // f1 = x2 @ Wf1 + bf1
    gemm3_k<192, false><<<dim3(GB, FH / 64), 256, 0, stream>>>(h2, wt_f1, bf1, f1, N, FH);
    colstats_k<512><<<512, 256, 0, stream>>>(f1, sum3, sq3, N);
    // g2 = gelu(BN(f1))  (in-place)
    bn_apply_k<512, true, false, false, false><<<(int)(((size_t)N * FH / 8 + 255) / 256), 256, 0, stream>>>(
        f1, f1, nullptr, sum3, sq3, gf1, bef1, N, 512, 0, invN);
    // h4 = g2 @ Wf2 + bf2
    gemm3_k<512, false><<<dim3(GB, C / 64), 256, 0, stream>>>(f1, wt_f2, bf2, h4, N, C);
    colstats_k<192><<<512, 192, 0, stream>>>(h4, sum4, sq4, N);
    // out = BN(h4) + x2  (fp32 out)
    bn_apply_k<192, false, true, false, true><<<(int)(((size_t)N * C / 8 + 255) / 256), 256, 0, stream>>>(
        h4, d_out, h2, sum4, sq4, gf2, bef2, N, 192, 0, invN);
}

// Round 3
// 842.595 us; speedup vs baseline: 1.1637x; 1.0141x over previous
//
#include <hip/hip_runtime.h>
#include <math.h>

// ---------------- types ----------------
typedef __bf16 bf16x8 __attribute__((ext_vector_type(8)));
typedef float  floatx4 __attribute__((ext_vector_type(4)));

__device__ inline float bf_lo(unsigned u){ return __uint_as_float(u << 16); }
__device__ inline float bf_hi(unsigned u){ return __uint_as_float(u & 0xffff0000u); }
__device__ inline unsigned short f2bf_u(float f){
    unsigned u = __float_as_uint(f);
    return (unsigned short)((u + 0x7fffu + ((u >> 16) & 1u)) >> 16);   // RNE
}
__device__ inline unsigned pack2(float a, float b){
    return (unsigned)f2bf_u(a) | ((unsigned)f2bf_u(b) << 16);
}
__device__ inline float gelu_f(float v){
    return 0.5f * v * (1.f + erff(v * 0.70710678118654752f));
}
__device__ inline void gload_lds16(const void* g, void* l){
    __builtin_amdgcn_global_load_lds(
        (const __attribute__((address_space(1))) unsigned int*)g,
        (__attribute__((address_space(3))) unsigned int*)l, 16, 0, 0);
}

// ---------------- utility ----------------
__global__ void zero_k(int* __restrict__ p, int n){
    int i = blockIdx.x * 256 + threadIdx.x;
    if (i < n) p[i] = 0;
}

__global__ void xcast_k(const float* __restrict__ x, unsigned short* __restrict__ xb, long n8){
    long i = (long)blockIdx.x * 256 + threadIdx.x;
    if (i < n8){
        const float4* p = (const float4*)(x + i * 8);
        float4 a = p[0], b = p[1];
        uint4 o;
        o.x = pack2(a.x, a.y); o.y = pack2(a.z, a.w);
        o.z = pack2(b.x, b.y); o.w = pack2(b.z, b.w);
        *(uint4*)(xb + i * 8) = o;
    }
}

// Wt[n*ostride + ooffs + k] = W[k][n], bf16
__global__ void wprep_k(const float* __restrict__ W, unsigned short* __restrict__ Wt,
                        int K, int Ncols, int ostride, int ooffs){
    int idx = blockIdx.x * 256 + threadIdx.x;
    if (idx < K * Ncols){
        int k = idx / Ncols, n = idx - k * Ncols;
        Wt[(size_t)n * ostride + ooffs + k] = f2bf_u(W[idx]);
    }
}

// ---------------- bucketed CSR build ----------------
// Buckets of RB=512 consecutive dst nodes (bucket = dst >> 9). nbuk <= 256.
// Counters in bcnt/bcur are padded to one per 64B line (stride 16 ints).

#define RBSH 9
#define RB   512
#define PCH  8192   // edges per bpart block

// global bucket histogram, LDS-aggregated
__global__ __launch_bounds__(256)
void bhist_k(const int* __restrict__ dst, int* __restrict__ bcnt, int E){
    __shared__ int h[256];
    for (int i = threadIdx.x; i < 256; i += 256) h[i] = 0;
    __syncthreads();
    for (long i = (long)blockIdx.x * 256 + threadIdx.x; i < E; i += (long)gridDim.x * 256)
        atomicAdd(&h[dst[i] >> RBSH], 1);
    __syncthreads();
    int v = h[threadIdx.x];
    if (v) atomicAdd(&bcnt[threadIdx.x * 16], v);
}

// exclusive scan over nbuk bucket counts; init padded cursors
__global__ void bscan_k(const int* __restrict__ bcnt, int* __restrict__ bbase,
                        int* __restrict__ bcur, int nbuk, int E){
    __shared__ int s[256];
    const int t = threadIdx.x;
    int v = (t < nbuk) ? bcnt[t * 16] : 0;
    s[t] = v; __syncthreads();
    for (int d = 1; d < 256; d <<= 1){
        int tt = (t >= d) ? s[t - d] : 0;
        __syncthreads();
        s[t] += tt;
        __syncthreads();
    }
    int excl = s[t] - v;
    if (t < nbuk){ bbase[t] = excl; bcur[t * 16] = excl; }
    if (t == 0) bbase[nbuk] = E;
}

// partition edges into bucket-grouped (src,dst) pairs.
// Per-block LDS hist + scan + one reservation atomic per (block,bucket);
// a block's pairs for one bucket land contiguously (~336B runs).
__global__ __launch_bounds__(512)
void bpart_k(const int* __restrict__ src, const int* __restrict__ dst,
             int* __restrict__ bcur, int2* __restrict__ pairs, int E){
    __shared__ int h[256];
    __shared__ int s[256];
    __shared__ int cur[256];
    const int t = threadIdx.x;
    const int base = blockIdx.x * PCH;
    const int cnt = min(PCH, E - base);
    if (t < 256) h[t] = 0;
    __syncthreads();
    for (int i = t; i < cnt; i += 512)
        atomicAdd(&h[dst[base + i] >> RBSH], 1);
    __syncthreads();
    if (t < 256) s[t] = h[t];
    __syncthreads();
    for (int d = 1; d < 256; d <<= 1){
        int tt = 0;
        if (t < 256 && t >= d) tt = s[t - d];
        __syncthreads();
        if (t < 256) s[t] += tt;
        __syncthreads();
    }
    if (t < 256){
        int myc = h[t];
        int g = 0;
        if (myc) g = atomicAdd(&bcur[t * 16], myc);
        cur[t] = g;
    }
    __syncthreads();
    for (int i = t; i < cnt; i += 512){
        int d = dst[base + i];
        int b = d >> RBSH;
        int r = atomicAdd(&cur[b], 1);
        pairs[r] = make_int2(src[base + i], d);
    }
}

// per-bucket CSR finalize: offsets (coalesced) + esrc scatter within the
// bucket's own ~32KB region (L2-resident, full lines -> streamed writeback).
__global__ __launch_bounds__(1024)
void bbuild_k(const int2* __restrict__ pairs, const int* __restrict__ bbase,
              int* __restrict__ offsets, int* __restrict__ esrc, int N, int E){
    __shared__ int h[RB];
    __shared__ int s[RB];
    const int b = blockIdx.x;
    const int t = threadIdx.x;
    const int p0 = bbase[b], p1 = bbase[b + 1];
    if (t < RB) h[t] = 0;
    __syncthreads();
    for (int i = p0 + t; i < p1; i += 1024)
        atomicAdd(&h[pairs[i].y & (RB - 1)], 1);
    __syncthreads();
    int v = 0;
    if (t < RB){ v = h[t]; s[t] = v; }
    __syncthreads();
    for (int d = 1; d < RB; d <<= 1){
        int tt = 0;
        if (t < RB && t >= d) tt = s[t - d];
        __syncthreads();
        if (t < RB) s[t] += tt;
        __syncthreads();
    }
    if (t < RB){
        int node = (b << RBSH) + t;
        int excl = p0 + s[t] - v;
        if (node < N) offsets[node] = excl;
        h[t] = excl;                       // reuse hist as cursor
    }
    __syncthreads();
    for (int i = p0 + t; i < p1; i += 1024){
        int2 pr = pairs[i];
        int r = atomicAdd(&h[pr.y & (RB - 1)], 1);
        esrc[r] = pr.x;
    }
    if (b == 0 && t == 0) offsets[N] = E;
}

// ---------------- aggregation into AG[:,0:256]; hbn = AG+256, both row-stride 512 ----------------
// 8-deep batched gather: 8 independent row-loads in flight per iteration
// (latency-bound fix; tail edges predicated via mask-FMA so unroll is static).
__global__ __launch_bounds__(256)
void agg_k(const unsigned short* __restrict__ hbn, const int* __restrict__ offsets,
           const int* __restrict__ esrc, unsigned short* __restrict__ aggout, int N){
    const int lane = threadIdx.x & 63;
    const int node = blockIdx.x * 4 + (threadIdx.x >> 6);
    if (node >= N) return;
    const int off = offsets[node];
    const int end = offsets[node + 1];
    float a0 = 0.f, a1 = 0.f, a2 = 0.f, a3 = 0.f;
    const unsigned short* hb = hbn + lane * 4;
    for (int c = off; c < end; c += 64){
        const int e = c + lane;
        int sl = (e < end) ? esrc[e] : 0;
        const int cnt = min(64, end - c);
        for (int j = 0; j < cnt; j += 8){
            int   s[8];
            float m[8];
            uint2 u[8];
#pragma unroll
            for (int k = 0; k < 8; ++k){
                s[k] = __shfl(sl, j + k);
                m[k] = (j + k < cnt) ? 1.f : 0.f;
            }
#pragma unroll
            for (int k = 0; k < 8; ++k)
                u[k] = *(const uint2*)(hb + (size_t)s[k] * 512);
#pragma unroll
            for (int k = 0; k < 8; ++k){
                a0 = fmaf(m[k], bf_lo(u[k].x), a0);
                a1 = fmaf(m[k], bf_hi(u[k].x), a1);
                a2 = fmaf(m[k], bf_lo(u[k].y), a2);
                a3 = fmaf(m[k], bf_hi(u[k].y), a3);
            }
        }
    }
    uint2 o; o.x = pack2(a0, a1); o.y = pack2(a2, a3);
    *(uint2*)(aggout + (size_t)node * 512 + lane * 4) = o;
}

// ---------------- GEMM v3 (m97 structure, swapped operands) ----------------
// C[M][NCOLS] = A[M][K](bf16) @ W, W given as Bt[n][k] bf16 row-stride K.
// Tile BM=128 x BN=64 x BK=64; 4 waves, wave w owns rows [w*32, w*32+32).
// Operand swap: A-operand = weight frag (m-index = out-col), B-operand = X frag
// (n-index = node row). D: col(lane&15)=node, row(q4*4+r)=out-col → lane holds 4
// consecutive out-cols of one node → 8B stores.
template<int K, bool GELU_OUT>
__global__ __launch_bounds__(256)
void gemm3_k(const unsigned short* __restrict__ A, const unsigned short* __restrict__ Bt,
             const float* __restrict__ bias, unsigned short* __restrict__ Cp,
             long M, int NCOLS){
    __shared__ unsigned short Xs[128 * 64];   // [row][k]
    __shared__ unsigned short Ws[64 * 64];    // [col][k]
    const int t    = threadIdx.x;
    const int lane = t & 63;
    const int w    = t >> 6;
    const int r16  = lane & 15;
    const int q4   = lane >> 4;
    const long mbase = (long)blockIdx.x * 128;
    const int  cb    = blockIdx.y * 64;

    floatx4 acc[4][2];
#pragma unroll
    for (int ai = 0; ai < 4; ++ai)
#pragma unroll
        for (int bi = 0; bi < 2; ++bi) acc[ai][bi] = (floatx4)0.f;

    // staging lane geometry: 16B per lane; row = 8 rows/wave-iter
    const int lrow = w * 8 + (lane >> 3);
    const int lk   = (lane & 7) * 8;
    const unsigned short* ga = A  + (size_t)(mbase + lrow) * K + lk;
    const unsigned short* gb = Bt + (size_t)(cb + lrow) * K + lk;
    unsigned short* lx = Xs + w * 512 + lane * 8;
    unsigned short* lw = Ws + w * 512 + lane * 8;

    for (int kt = 0; kt < K; kt += 64){
#pragma unroll
        for (int i = 0; i < 4; ++i)
            gload_lds16(ga + (size_t)i * 32 * K + kt, lx + i * 2048);
#pragma unroll
        for (int j = 0; j < 2; ++j)
            gload_lds16(gb + (size_t)j * 32 * K + kt, lw + j * 2048);
        asm volatile("s_waitcnt vmcnt(0)" ::: "memory");
        __syncthreads();
#pragma unroll
        for (int kc = 0; kc < 64; kc += 32){
            bf16x8 wf[4], xf[2];
#pragma unroll
            for (int ai = 0; ai < 4; ++ai)
                wf[ai] = *(const bf16x8*)(Ws + (ai * 16 + r16) * 64 + kc + q4 * 8);
#pragma unroll
            for (int bi = 0; bi < 2; ++bi)
                xf[bi] = *(const bf16x8*)(Xs + (w * 32 + bi * 16 + r16) * 64 + kc + q4 * 8);
#pragma unroll
            for (int ai = 0; ai < 4; ++ai)
#pragma unroll
                for (int bi = 0; bi < 2; ++bi)
                    acc[ai][bi] = __builtin_amdgcn_mfma_f32_16x16x32_bf16(
                        wf[ai], xf[bi], acc[ai][bi], 0, 0, 0);
        }
        __syncthreads();
    }

    // epilogue: bias (+gelu), 8B vector stores
    float4 bv[4];
#pragma unroll
    for (int ai = 0; ai < 4; ++ai)
        bv[ai] = *(const float4*)(bias + cb + ai * 16 + q4 * 4);
#pragma unroll
    for (int bi = 0; bi < 2; ++bi){
        long node = mbase + w * 32 + bi * 16 + r16;
        if (node < M){
            unsigned short* cp = Cp + (size_t)node * NCOLS + cb;
#pragma unroll
            for (int ai = 0; ai < 4; ++ai){
                float v0 = acc[ai][bi][0] + bv[ai].x;
                float v1 = acc[ai][bi][1] + bv[ai].y;
                float v2 = acc[ai][bi][2] + bv[ai].z;
                float v3 = acc[ai][bi][3] + bv[ai].w;
                if constexpr (GELU_OUT){
                    v0 = gelu_f(v0); v1 = gelu_f(v1); v2 = gelu_f(v2); v3 = gelu_f(v3);
                }
                uint2 o; o.x = pack2(v0, v1); o.y = pack2(v2, v3);
                *(uint2*)(cp + ai * 16 + q4 * 4) = o;
            }
        }
    }
}

// ---------------- column stats: gsum[c] += sum rows, gsq[c] += sum rows^2 ----------------
template<int NCOLS>
__global__ void colstats_k(const unsigned short* __restrict__ in,
                           float* __restrict__ gsum, float* __restrict__ gsq, long nrows){
    constexpr int TPR  = NCOLS / 8;
    constexpr int BDIM = (NCOLS == 192) ? 192 : 256;
    constexpr int ROWS = BDIM / TPR;
    __shared__ float sS[ROWS * NCOLS], sQ[ROWS * NCOLS];
    const int t  = threadIdx.x;
    const int c8 = (t % TPR) * 8;
    const int r  = t / TPR;
    float s[8], q[8];
#pragma unroll
    for (int j = 0; j < 8; ++j){ s[j] = 0.f; q[j] = 0.f; }
    for (long row = (long)blockIdx.x * ROWS + r; row < nrows; row += (long)gridDim.x * ROWS){
        uint4 u = *(const uint4*)(in + row * NCOLS + c8);
        float v[8];
        v[0] = bf_lo(u.x); v[1] = bf_hi(u.x); v[2] = bf_lo(u.y); v[3] = bf_hi(u.y);
        v[4] = bf_lo(u.z); v[5] = bf_hi(u.z); v[6] = bf_lo(u.w); v[7] = bf_hi(u.w);
#pragma unroll
        for (int j = 0; j < 8; ++j){ s[j] += v[j]; q[j] += v[j] * v[j]; }
    }
#pragma unroll
    for (int j = 0; j < 8; ++j){ sS[r * NCOLS + c8 + j] = s[j]; sQ[r * NCOLS + c8 + j] = q[j]; }
    __syncthreads();
    for (int c = t; c < NCOLS; c += BDIM){
        float as = 0.f, aq = 0.f;
#pragma unroll
        for (int rr = 0; rr < ROWS; ++rr){ as += sS[rr * NCOLS + c]; aq += sQ[rr * NCOLS + c]; }
        atomicAdd(&gsum[c], as);
        atomicAdd(&gsq[c],  aq);
    }
}

// ---------------- BN apply (+gelu, +residual, strided out, fp32/bf16 out) ----------------
template<int NCOLS, bool GELU_OUT, bool RES, bool RES_F32, bool OUT_F32>
__global__ __launch_bounds__(256)
void bn_apply_k(const unsigned short* __restrict__ in, void* __restrict__ outv,
                const void* __restrict__ resv,
                const float* __restrict__ gsum, const float* __restrict__ gsq,
                const float* __restrict__ gamma, const float* __restrict__ beta,
                long nrows, int ostride, int ooffs, float invN){
    __shared__ float s_scale[NCOLS], s_shift[NCOLS];
    for (int c = threadIdx.x; c < NCOLS; c += 256){
        float mean = gsum[c] * invN;
        float var  = gsq[c] * invN - mean * mean;
        float sc   = gamma[c] * rsqrtf(var + 1e-5f);
        s_scale[c] = sc;
        s_shift[c] = beta[c] - mean * sc;
    }
    __syncthreads();
    long i8 = ((long)blockIdx.x * 256 + threadIdx.x) * 8;
    if (i8 >= nrows * (long)NCOLS) return;
    long row  = i8 / NCOLS;
    int  col0 = (int)(i8 - row * NCOLS);
    uint4 u = *(const uint4*)(in + i8);
    float v[8];
    v[0] = bf_lo(u.x); v[1] = bf_hi(u.x); v[2] = bf_lo(u.y); v[3] = bf_hi(u.y);
    v[4] = bf_lo(u.z); v[5] = bf_hi(u.z); v[6] = bf_lo(u.w); v[7] = bf_hi(u.w);
#pragma unroll
    for (int j = 0; j < 8; ++j){
        v[j] = v[j] * s_scale[col0 + j] + s_shift[col0 + j];
        if constexpr (GELU_OUT) v[j] = gelu_f(v[j]);
    }
    if constexpr (RES){
        if constexpr (RES_F32){
            const float4* rp = (const float4*)((const float*)resv + i8);
            float4 r0 = rp[0], r1 = rp[1];
            v[0] += r0.x; v[1] += r0.y; v[2] += r0.z; v[3] += r0.w;
            v[4] += r1.x; v[5] += r1.y; v[6] += r1.z; v[7] += r1.w;
        } else {
            uint4 r = *(const uint4*)((const unsigned short*)resv + i8);
            v[0] += bf_lo(r.x); v[1] += bf_hi(r.x); v[2] += bf_lo(r.y); v[3] += bf_hi(r.y);
            v[4] += bf_lo(r.z); v[5] += bf_hi(r.z); v[6] += bf_lo(r.w); v[7] += bf_hi(r.w);
        }
    }
    long opos = row * ostride + ooffs + col0;
    if constexpr (OUT_F32){
        float4* op = (float4*)((float*)outv + opos);
        op[0] = make_float4(v[0], v[1], v[2], v[3]);
        op[1] = make_float4(v[4], v[5], v[6], v[7]);
    } else {
        uint4 o;
        o.x = pack2(v[0], v[1]); o.y = pack2(v[2], v[3]);
        o.z = pack2(v[4], v[5]); o.w = pack2(v[6], v[7]);
        *(uint4*)((unsigned short*)outv + opos) = o;
    }
}

// ---------------- host ----------------
extern "C" void kernel_launch(void* const* d_in, const int* in_sizes, int n_in,
                              void* d_out, int out_size, void* d_ws, size_t ws_size,
                              hipStream_t stream){
    const int C = 192, GH = 256, FH = 512;
    const float* x    = (const float*)d_in[0];
    const int*   ei   = (const int*)d_in[1];
    const float* Wg1  = (const float*)d_in[2];
    const float* bg1  = (const float*)d_in[3];
    const float* gg1  = (const float*)d_in[4];
    const float* beg1 = (const float*)d_in[5];
    const float* Wrel = (const float*)d_in[6];
    const float* brel = (const float*)d_in[7];
    const float* Wroot= (const float*)d_in[8];
    const float* Wg2  = (const float*)d_in[9];
    const float* bg2  = (const float*)d_in[10];
    const float* gg2  = (const float*)d_in[11];
    const float* beg2 = (const float*)d_in[12];
    const float* Wf1  = (const float*)d_in[13];
    const float* bf1  = (const float*)d_in[14];
    const float* gf1  = (const float*)d_in[15];
    const float* bef1 = (const float*)d_in[16];
    const float* Wf2  = (const float*)d_in[17];
    const float* bf2  = (const float*)d_in[18];
    const float* gf2  = (const float*)d_in[19];
    const float* bef2 = (const float*)d_in[20];

    const int N = in_sizes[0] / C;
    const int E = in_sizes[1] / 2;
    const int* e_src = ei;
    const int* e_dst = ei + E;

    // ---- workspace arena (~214 MB). Big A-source buffers placed BEFORE the
    // int buffers so gemm3's ≤130 KB staging over-read stays in-arena. ----
    char* wp = (char*)d_ws;
    auto carve = [&](size_t bytes) -> void* {
        void* p = (void*)wp; wp += (bytes + 255) & ~(size_t)255; return p;
    };
    unsigned short* wt_g1 = (unsigned short*)carve((size_t)GH * C * 2);     // [256][192]
    unsigned short* wt_rr = (unsigned short*)carve((size_t)GH * 512 * 2);   // [256][512] = [Wrel^T|Wroot^T]
    unsigned short* wt_g2 = (unsigned short*)carve((size_t)C * GH * 2);     // [192][256]
    unsigned short* wt_f1 = (unsigned short*)carve((size_t)FH * C * 2);     // [512][192]
    unsigned short* wt_f2 = (unsigned short*)carve((size_t)C * FH * 2);     // [192][512]
    float* stats = (float*)carve(2 * (size_t)(GH + C + FH + C) * 4);
    float* sum1 = stats;        float* sq1 = sum1 + GH;
    float* sum2 = sq1 + GH;     float* sq2 = sum2 + C;
    float* sum3 = sq2 + C;      float* sq3 = sum3 + FH;
    float* sum4 = sq3 + FH;     float* sq4 = sum4 + C;
    // buf0 [N,512]: pairs (CSR build, dies before h1) -> h1[N,256] -> g[N,256] -> f1/g2[N,512]
    unsigned short* buf0  = (unsigned short*)carve((size_t)N * 512 * 2);
    // bufAG [N,512]: x_bf[N,192] (dies at g1) -> AG=[agg|hbn] -> h2/x2[N,192]@0, h4[N,192]@N*192
    unsigned short* bufAG = (unsigned short*)carve((size_t)N * 512 * 2);
    int* offsets = (int*)carve((size_t)(N + 1) * 4);
    int* esrc    = (int*)carve((size_t)E * 4);
    int* bcnt    = (int*)carve((size_t)256 * 16 * 4);   // padded: 1 counter / 64B line
    int* bbase   = (int*)carve((size_t)257 * 4);
    int* bcur    = (int*)carve((size_t)256 * 16 * 4);   // padded
    unsigned short* x_bf = bufAG;                       // [N,192] overlay, dead before AG written
    int2* pairs = (int2*)buf0;                          // [E] overlay, dead before h1 written
    unsigned short* h1  = buf0;
    unsigned short* g   = buf0;
    unsigned short* f1  = buf0;                          // also g2 (in-place BN)
    unsigned short* AG  = bufAG;
    unsigned short* h2  = bufAG;                         // also x2 (in-place BN+res)
    unsigned short* h4  = bufAG + (size_t)N * C;
    (void)ws_size; (void)n_in; (void)out_size;

    const float invN = 1.0f / (float)N;
    const int GB = (N + 127) / 128;   // gemm3 grid.x
    const int nbuk = (N + RB - 1) >> RBSH;   // <=256 for N<=131072

    // weight prep
    wprep_k<<<(C * GH + 255) / 256, 256, 0, stream>>>(Wg1, wt_g1, C, GH, C, 0);
    wprep_k<<<(GH * GH + 255) / 256, 256, 0, stream>>>(Wrel, wt_rr, GH, GH, 512, 0);
    wprep_k<<<(GH * GH + 255) / 256, 256, 0, stream>>>(Wroot, wt_rr, GH, GH, 512, GH);
    wprep_k<<<(GH * C + 255) / 256, 256, 0, stream>>>(Wg2, wt_g2, GH, C, GH, 0);
    wprep_k<<<(C * FH + 255) / 256, 256, 0, stream>>>(Wf1, wt_f1, C, FH, C, 0);
    wprep_k<<<(FH * C + 255) / 256, 256, 0, stream>>>(Wf2, wt_f2, FH, C, FH, 0);

    const int nstats = 2 * (GH + C + FH + C);
    zero_k<<<(nstats + 255) / 256, 256, 0, stream>>>((int*)stats, nstats);
    zero_k<<<(256 * 16 + 255) / 256, 256, 0, stream>>>(bcnt, 256 * 16);

    // bucketed CSR build
    bhist_k<<<1024, 256, 0, stream>>>(e_dst, bcnt, E);
    bscan_k<<<1, 256, 0, stream>>>(bcnt, bbase, bcur, nbuk, E);
    bpart_k<<<(E + PCH - 1) / PCH, 512, 0, stream>>>(e_src, e_dst, bcur, pairs, E);
    bbuild_k<<<nbuk, 1024, 0, stream>>>(pairs, bbase, offsets, esrc, N, E);

    // x -> bf16 (for g1 GEMM A-input)
    xcast_k<<<(int)(((size_t)N * C / 8 + 255) / 256), 256, 0, stream>>>(x, x_bf, (long)N * C / 8);

    // ---- Grapher ----
    // h1 = x @ Wg1 + bg1
    gemm3_k<192, false><<<dim3(GB, GH / 64), 256, 0, stream>>>(x_bf, wt_g1, bg1, h1, N, GH);
    colstats_k<256><<<512, 256, 0, stream>>>(h1, sum1, sq1, N);
    // hbn = BN(h1) -> AG[:,256:512]   (x_bf dies here)
    bn_apply_k<256, false, false, false, false><<<(int)(((size_t)N * GH / 8 + 255) / 256), 256, 0, stream>>>(
        h1, AG, nullptr, sum1, sq1, gg1, beg1, N, 512, 256, invN);
    // agg -> AG[:,0:256]
    agg_k<<<(N + 3) / 4, 256, 0, stream>>>(AG + 256, offsets, esrc, AG, N);
    // g = gelu([agg|hbn] @ [Wrel;Wroot] + brel)
    gemm3_k<512, true><<<dim3(GB, GH / 64), 256, 0, stream>>>(AG, wt_rr, brel, g, N, GH);
    // h2 = g @ Wg2 + bg2
    gemm3_k<256, false><<<dim3(GB, C / 64), 256, 0, stream>>>(g, wt_g2, bg2, h2, N, C);
    colstats_k<192><<<512, 192, 0, stream>>>(h2, sum2, sq2, N);
    // x2 = BN(h2) + x   (in-place)
    bn_apply_k<192, false, true, true, false><<<(int)(((size_t)N * C / 8 + 255) / 256), 256, 0, stream>>>(
        h2, h2, x, sum2, sq2, gg2, beg2, N, 192, 0, invN);

    // ---- FFN ----
    // f1 = x2 @ Wf1 + bf1
    gemm3_k<192, false><<<dim3(GB, FH / 64), 256, 0, stream>>>(h2, wt_f1, bf1, f1, N, FH);
    colstats_k<512><<<512, 256, 0, stream>>>(f1, sum3, sq3, N);
    // g2 = gelu(BN(f1))  (in-place)
    bn_apply_k<512, true, false, false, false><<<(int)(((size_t)N * FH / 8 + 255) / 256), 256, 0, stream>>>(
        f1, f1, nullptr, sum3, sq3, gf1, bef1, N, 512, 0, invN);
    // h4 = g2 @ Wf2 + bf2
    gemm3_k<512, false><<<dim3(GB, C / 64), 256, 0, stream>>>(f1, wt_f2, bf2, h4, N, C);
    colstats_k<192><<<512, 192, 0, stream>>>(h4, sum4, sq4, N);
    // out = BN(h4) + x2  (fp32 out)
    bn_apply_k<192, false, true, false, true><<<(int)(((size_t)N * C / 8 + 255) / 256), 256, 0, stream>>>(
        h4, d_out, h2, sum4, sq4, gf2, bef2, N, 192, 0, invN);
}

// Round 4
// 842.145 us; speedup vs baseline: 1.1643x; 1.0005x over previous
//
#include <hip/hip_runtime.h>
#include <math.h>

// ---------------- types ----------------
typedef __bf16 bf16x8 __attribute__((ext_vector_type(8)));
typedef float  floatx4 __attribute__((ext_vector_type(4)));

__device__ inline float bf_lo(unsigned u){ return __uint_as_float(u << 16); }
__device__ inline float bf_hi(unsigned u){ return __uint_as_float(u & 0xffff0000u); }
__device__ inline unsigned short f2bf_u(float f){
    unsigned u = __float_as_uint(f);
    return (unsigned short)((u + 0x7fffu + ((u >> 16) & 1u)) >> 16);   // RNE
}
__device__ inline unsigned pack2(float a, float b){
    return (unsigned)f2bf_u(a) | ((unsigned)f2bf_u(b) << 16);
}
__device__ inline float gelu_f(float v){
    return 0.5f * v * (1.f + erff(v * 0.70710678118654752f));
}
__device__ inline void gload_lds16(const void* g, void* l){
    __builtin_amdgcn_global_load_lds(
        (const __attribute__((address_space(1))) unsigned int*)g,
        (__attribute__((address_space(3))) unsigned int*)l, 16, 0, 0);
}

// ---------------- utility ----------------
__global__ void zero_k(int* __restrict__ p, int n){
    int i = blockIdx.x * 256 + threadIdx.x;
    if (i < n) p[i] = 0;
}

__global__ void xcast_k(const float* __restrict__ x, unsigned short* __restrict__ xb, long n8){
    long i = (long)blockIdx.x * 256 + threadIdx.x;
    if (i < n8){
        const float4* p = (const float4*)(x + i * 8);
        float4 a = p[0], b = p[1];
        uint4 o;
        o.x = pack2(a.x, a.y); o.y = pack2(a.z, a.w);
        o.z = pack2(b.x, b.y); o.w = pack2(b.z, b.w);
        *(uint4*)(xb + i * 8) = o;
    }
}

// Wt[n*ostride + ooffs + k] = W[k][n], bf16
__global__ void wprep_k(const float* __restrict__ W, unsigned short* __restrict__ Wt,
                        int K, int Ncols, int ostride, int ooffs){
    int idx = blockIdx.x * 256 + threadIdx.x;
    if (idx < K * Ncols){
        int k = idx / Ncols, n = idx - k * Ncols;
        Wt[(size_t)n * ostride + ooffs + k] = f2bf_u(W[idx]);
    }
}

// ---------------- bucketed CSR build ----------------
// Buckets of RB=512 consecutive dst nodes (bucket = dst >> 9). nbuk <= 256.
// Counters in bcnt/bcur are padded to one per 64B line (stride 16 ints).

#define RBSH 9
#define RB   512
#define PCH  8192   // edges per bpart block

// global bucket histogram, LDS-aggregated
__global__ __launch_bounds__(256)
void bhist_k(const int* __restrict__ dst, int* __restrict__ bcnt, int E){
    __shared__ int h[256];
    for (int i = threadIdx.x; i < 256; i += 256) h[i] = 0;
    __syncthreads();
    for (long i = (long)blockIdx.x * 256 + threadIdx.x; i < E; i += (long)gridDim.x * 256)
        atomicAdd(&h[dst[i] >> RBSH], 1);
    __syncthreads();
    int v = h[threadIdx.x];
    if (v) atomicAdd(&bcnt[threadIdx.x * 16], v);
}

// exclusive scan over nbuk bucket counts; init padded cursors
__global__ void bscan_k(const int* __restrict__ bcnt, int* __restrict__ bbase,
                        int* __restrict__ bcur, int nbuk, int E){
    __shared__ int s[256];
    const int t = threadIdx.x;
    int v = (t < nbuk) ? bcnt[t * 16] : 0;
    s[t] = v; __syncthreads();
    for (int d = 1; d < 256; d <<= 1){
        int tt = (t >= d) ? s[t - d] : 0;
        __syncthreads();
        s[t] += tt;
        __syncthreads();
    }
    int excl = s[t] - v;
    if (t < nbuk){ bbase[t] = excl; bcur[t * 16] = excl; }
    if (t == 0) bbase[nbuk] = E;
}

// partition edges into bucket-grouped (src,dst) pairs.
// Per-block LDS hist + scan + one reservation atomic per (block,bucket);
// a block's pairs for one bucket land contiguously (~336B runs).
__global__ __launch_bounds__(512)
void bpart_k(const int* __restrict__ src, const int* __restrict__ dst,
             int* __restrict__ bcur, int2* __restrict__ pairs, int E){
    __shared__ int h[256];
    __shared__ int s[256];
    __shared__ int cur[256];
    const int t = threadIdx.x;
    const int base = blockIdx.x * PCH;
    const int cnt = min(PCH, E - base);
    if (t < 256) h[t] = 0;
    __syncthreads();
    for (int i = t; i < cnt; i += 512)
        atomicAdd(&h[dst[base + i] >> RBSH], 1);
    __syncthreads();
    if (t < 256) s[t] = h[t];
    __syncthreads();
    for (int d = 1; d < 256; d <<= 1){
        int tt = 0;
        if (t < 256 && t >= d) tt = s[t - d];
        __syncthreads();
        if (t < 256) s[t] += tt;
        __syncthreads();
    }
    if (t < 256){
        int myc = h[t];
        int g = 0;
        if (myc) g = atomicAdd(&bcur[t * 16], myc);
        cur[t] = g;
    }
    __syncthreads();
    for (int i = t; i < cnt; i += 512){
        int d = dst[base + i];
        int b = d >> RBSH;
        int r = atomicAdd(&cur[b], 1);
        pairs[r] = make_int2(src[base + i], d);
    }
}

// per-bucket CSR finalize: offsets (coalesced) + esrc scatter within the
// bucket's own ~32KB region (L2-resident, full lines -> streamed writeback).
__global__ __launch_bounds__(1024)
void bbuild_k(const int2* __restrict__ pairs, const int* __restrict__ bbase,
              int* __restrict__ offsets, int* __restrict__ esrc, int N, int E){
    __shared__ int h[RB];
    __shared__ int s[RB];
    const int b = blockIdx.x;
    const int t = threadIdx.x;
    const int p0 = bbase[b], p1 = bbase[b + 1];
    if (t < RB) h[t] = 0;
    __syncthreads();
    for (int i = p0 + t; i < p1; i += 1024)
        atomicAdd(&h[pairs[i].y & (RB - 1)], 1);
    __syncthreads();
    int v = 0;
    if (t < RB){ v = h[t]; s[t] = v; }
    __syncthreads();
    for (int d = 1; d < RB; d <<= 1){
        int tt = 0;
        if (t < RB && t >= d) tt = s[t - d];
        __syncthreads();
        if (t < RB) s[t] += tt;
        __syncthreads();
    }
    if (t < RB){
        int node = (b << RBSH) + t;
        int excl = p0 + s[t] - v;
        if (node < N) offsets[node] = excl;
        h[t] = excl;                       // reuse hist as cursor
    }
    __syncthreads();
    for (int i = p0 + t; i < p1; i += 1024){
        int2 pr = pairs[i];
        int r = atomicAdd(&h[pr.y & (RB - 1)], 1);
        esrc[r] = pr.x;
    }
    if (b == 0 && t == 0) offsets[N] = E;
}

// ---------------- aggregation into AG[:,0:256]; hbn = AG+256, both row-stride 512 ----------------
// 2 edges per wave-load (32 lanes x 16B each), 8 loads deep -> 16 edges in
// flight per wave. Tail edges predicated via mask-FMA; cross-half combine at
// the end via shfl_xor(32).
__global__ __launch_bounds__(256)
void agg_k(const unsigned short* __restrict__ hbn, const int* __restrict__ offsets,
           const int* __restrict__ esrc, unsigned short* __restrict__ aggout, int N){
    const int lane = threadIdx.x & 63;
    const int node = blockIdx.x * 4 + (threadIdx.x >> 6);
    if (node >= N) return;
    const int off  = offsets[node];
    const int end  = offsets[node + 1];
    const int half = lane >> 5;          // 0: even edges, 1: odd edges
    const int l32  = lane & 31;
    float a[8];
#pragma unroll
    for (int j = 0; j < 8; ++j) a[j] = 0.f;
    const unsigned short* hb = hbn + l32 * 8;    // 16B per lane, 32 lanes = 512B row
    for (int c = off; c < end; c += 64){
        const int e = c + lane;
        int sl = (e < end) ? esrc[e] : 0;
        const int cnt = min(64, end - c);
        for (int j = 0; j < cnt; j += 16){
            int   s[8];
            float m[8];
            uint4 u[8];
#pragma unroll
            for (int k = 0; k < 8; ++k){
                const int idx = j + 2 * k + half;
                s[k] = __shfl(sl, idx);
                m[k] = (idx < cnt) ? 1.f : 0.f;
            }
#pragma unroll
            for (int k = 0; k < 8; ++k)
                u[k] = *(const uint4*)(hb + (size_t)s[k] * 512);
#pragma unroll
            for (int k = 0; k < 8; ++k){
                a[0] = fmaf(m[k], bf_lo(u[k].x), a[0]);
                a[1] = fmaf(m[k], bf_hi(u[k].x), a[1]);
                a[2] = fmaf(m[k], bf_lo(u[k].y), a[2]);
                a[3] = fmaf(m[k], bf_hi(u[k].y), a[3]);
                a[4] = fmaf(m[k], bf_lo(u[k].z), a[4]);
                a[5] = fmaf(m[k], bf_hi(u[k].z), a[5]);
                a[6] = fmaf(m[k], bf_lo(u[k].w), a[6]);
                a[7] = fmaf(m[k], bf_hi(u[k].w), a[7]);
            }
        }
    }
    // lanes l and l+32 hold the same 8 cols (for even/odd edge subsets)
#pragma unroll
    for (int j = 0; j < 8; ++j)
        a[j] += __shfl_xor(a[j], 32);
    if (half == 0){
        uint4 o;
        o.x = pack2(a[0], a[1]); o.y = pack2(a[2], a[3]);
        o.z = pack2(a[4], a[5]); o.w = pack2(a[6], a[7]);
        *(uint4*)(aggout + (size_t)node * 512 + l32 * 8) = o;
    }
}

// ---------------- GEMM v3 (m97 structure, swapped operands) ----------------
// C[M][NCOLS] = A[M][K](bf16) @ W, W given as Bt[n][k] bf16 row-stride K.
// Tile BM=128 x BN=64 x BK=64; 4 waves, wave w owns rows [w*32, w*32+32).
// Operand swap: A-operand = weight frag (m-index = out-col), B-operand = X frag
// (n-index = node row). D: col(lane&15)=node, row(q4*4+r)=out-col → lane holds 4
// consecutive out-cols of one node → 8B stores.
template<int K, bool GELU_OUT>
__global__ __launch_bounds__(256)
void gemm3_k(const unsigned short* __restrict__ A, const unsigned short* __restrict__ Bt,
             const float* __restrict__ bias, unsigned short* __restrict__ Cp,
             long M, int NCOLS){
    __shared__ unsigned short Xs[128 * 64];   // [row][k]
    __shared__ unsigned short Ws[64 * 64];    // [col][k]
    const int t    = threadIdx.x;
    const int lane = t & 63;
    const int w    = t >> 6;
    const int r16  = lane & 15;
    const int q4   = lane >> 4;
    const long mbase = (long)blockIdx.x * 128;
    const int  cb    = blockIdx.y * 64;

    floatx4 acc[4][2];
#pragma unroll
    for (int ai = 0; ai < 4; ++ai)
#pragma unroll
        for (int bi = 0; bi < 2; ++bi) acc[ai][bi] = (floatx4)0.f;

    // staging lane geometry: 16B per lane; row = 8 rows/wave-iter
    const int lrow = w * 8 + (lane >> 3);
    const int lk   = (lane & 7) * 8;
    const unsigned short* ga = A  + (size_t)(mbase + lrow) * K + lk;
    const unsigned short* gb = Bt + (size_t)(cb + lrow) * K + lk;
    unsigned short* lx = Xs + w * 512 + lane * 8;
    unsigned short* lw = Ws + w * 512 + lane * 8;

    for (int kt = 0; kt < K; kt += 64){
#pragma unroll
        for (int i = 0; i < 4; ++i)
            gload_lds16(ga + (size_t)i * 32 * K + kt, lx + i * 2048);
#pragma unroll
        for (int j = 0; j < 2; ++j)
            gload_lds16(gb + (size_t)j * 32 * K + kt, lw + j * 2048);
        asm volatile("s_waitcnt vmcnt(0)" ::: "memory");
        __syncthreads();
#pragma unroll
        for (int kc = 0; kc < 64; kc += 32){
            bf16x8 wf[4], xf[2];
#pragma unroll
            for (int ai = 0; ai < 4; ++ai)
                wf[ai] = *(const bf16x8*)(Ws + (ai * 16 + r16) * 64 + kc + q4 * 8);
#pragma unroll
            for (int bi = 0; bi < 2; ++bi)
                xf[bi] = *(const bf16x8*)(Xs + (w * 32 + bi * 16 + r16) * 64 + kc + q4 * 8);
#pragma unroll
            for (int ai = 0; ai < 4; ++ai)
#pragma unroll
                for (int bi = 0; bi < 2; ++bi)
                    acc[ai][bi] = __builtin_amdgcn_mfma_f32_16x16x32_bf16(
                        wf[ai], xf[bi], acc[ai][bi], 0, 0, 0);
        }
        __syncthreads();
    }

    // epilogue: bias (+gelu), 8B vector stores
    float4 bv[4];
#pragma unroll
    for (int ai = 0; ai < 4; ++ai)
        bv[ai] = *(const float4*)(bias + cb + ai * 16 + q4 * 4);
#pragma unroll
    for (int bi = 0; bi < 2; ++bi){
        long node = mbase + w * 32 + bi * 16 + r16;
        if (node < M){
            unsigned short* cp = Cp + (size_t)node * NCOLS + cb;
#pragma unroll
            for (int ai = 0; ai < 4; ++ai){
                float v0 = acc[ai][bi][0] + bv[ai].x;
                float v1 = acc[ai][bi][1] + bv[ai].y;
                float v2 = acc[ai][bi][2] + bv[ai].z;
                float v3 = acc[ai][bi][3] + bv[ai].w;
                if constexpr (GELU_OUT){
                    v0 = gelu_f(v0); v1 = gelu_f(v1); v2 = gelu_f(v2); v3 = gelu_f(v3);
                }
                uint2 o; o.x = pack2(v0, v1); o.y = pack2(v2, v3);
                *(uint2*)(cp + ai * 16 + q4 * 4) = o;
            }
        }
    }
}

// ---------------- column stats: gsum[c] += sum rows, gsq[c] += sum rows^2 ----------------
template<int NCOLS>
__global__ void colstats_k(const unsigned short* __restrict__ in,
                           float* __restrict__ gsum, float* __restrict__ gsq, long nrows){
    constexpr int TPR  = NCOLS / 8;
    constexpr int BDIM = (NCOLS == 192) ? 192 : 256;
    constexpr int ROWS = BDIM / TPR;
    __shared__ float sS[ROWS * NCOLS], sQ[ROWS * NCOLS];
    const int t  = threadIdx.x;
    const int c8 = (t % TPR) * 8;
    const int r  = t / TPR;
    float s[8], q[8];
#pragma unroll
    for (int j = 0; j < 8; ++j){ s[j] = 0.f; q[j] = 0.f; }
    for (long row = (long)blockIdx.x * ROWS + r; row < nrows; row += (long)gridDim.x * ROWS){
        uint4 u = *(const uint4*)(in + row * NCOLS + c8);
        float v[8];
        v[0] = bf_lo(u.x); v[1] = bf_hi(u.x); v[2] = bf_lo(u.y); v[3] = bf_hi(u.y);
        v[4] = bf_lo(u.z); v[5] = bf_hi(u.z); v[6] = bf_lo(u.w); v[7] = bf_hi(u.w);
#pragma unroll
        for (int j = 0; j < 8; ++j){ s[j] += v[j]; q[j] += v[j] * v[j]; }
    }
#pragma unroll
    for (int j = 0; j < 8; ++j){ sS[r * NCOLS + c8 + j] = s[j]; sQ[r * NCOLS + c8 + j] = q[j]; }
    __syncthreads();
    for (int c = t; c < NCOLS; c += BDIM){
        float as = 0.f, aq = 0.f;
#pragma unroll
        for (int rr = 0; rr < ROWS; ++rr){ as += sS[rr * NCOLS + c]; aq += sQ[rr * NCOLS + c]; }
        atomicAdd(&gsum[c], as);
        atomicAdd(&gsq[c],  aq);
    }
}

// ---------------- BN apply (+gelu, +residual, strided out, fp32/bf16 out) ----------------
template<int NCOLS, bool GELU_OUT, bool RES, bool RES_F32, bool OUT_F32>
__global__ __launch_bounds__(256)
void bn_apply_k(const unsigned short* __restrict__ in, void* __restrict__ outv,
                const void* __restrict__ resv,
                const float* __restrict__ gsum, const float* __restrict__ gsq,
                const float* __restrict__ gamma, const float* __restrict__ beta,
                long nrows, int ostride, int ooffs, float invN){
    __shared__ float s_scale[NCOLS], s_shift[NCOLS];
    for (int c = threadIdx.x; c < NCOLS; c += 256){
        float mean = gsum[c] * invN;
        float var  = gsq[c] * invN - mean * mean;
        float sc   = gamma[c] * rsqrtf(var + 1e-5f);
        s_scale[c] = sc;
        s_shift[c] = beta[c] - mean * sc;
    }
    __syncthreads();
    long i8 = ((long)blockIdx.x * 256 + threadIdx.x) * 8;
    if (i8 >= nrows * (long)NCOLS) return;
    long row  = i8 / NCOLS;
    int  col0 = (int)(i8 - row * NCOLS);
    uint4 u = *(const uint4*)(in + i8);
    float v[8];
    v[0] = bf_lo(u.x); v[1] = bf_hi(u.x); v[2] = bf_lo(u.y); v[3] = bf_hi(u.y);
    v[4] = bf_lo(u.z); v[5] = bf_hi(u.z); v[6] = bf_lo(u.w); v[7] = bf_hi(u.w);
#pragma unroll
    for (int j = 0; j < 8; ++j){
        v[j] = v[j] * s_scale[col0 + j] + s_shift[col0 + j];
        if constexpr (GELU_OUT) v[j] = gelu_f(v[j]);
    }
    if constexpr (RES){
        if constexpr (RES_F32){
            const float4* rp = (const float4*)((const float*)resv + i8);
            float4 r0 = rp[0], r1 = rp[1];
            v[0] += r0.x; v[1] += r0.y; v[2] += r0.z; v[3] += r0.w;
            v[4] += r1.x; v[5] += r1.y; v[6] += r1.z; v[7] += r1.w;
        } else {
            uint4 r = *(const uint4*)((const unsigned short*)resv + i8);
            v[0] += bf_lo(r.x); v[1] += bf_hi(r.x); v[2] += bf_lo(r.y); v[3] += bf_hi(r.y);
            v[4] += bf_lo(r.z); v[5] += bf_hi(r.z); v[6] += bf_lo(r.w); v[7] += bf_hi(r.w);
        }
    }
    long opos = row * ostride + ooffs + col0;
    if constexpr (OUT_F32){
        float4* op = (float4*)((float*)outv + opos);
        op[0] = make_float4(v[0], v[1], v[2], v[3]);
        op[1] = make_float4(v[4], v[5], v[6], v[7]);
    } else {
        uint4 o;
        o.x = pack2(v[0], v[1]); o.y = pack2(v[2], v[3]);
        o.z = pack2(v[4], v[5]); o.w = pack2(v[6], v[7]);
        *(uint4*)((unsigned short*)outv + opos) = o;
    }
}

// ---------------- host ----------------
extern "C" void kernel_launch(void* const* d_in, const int* in_sizes, int n_in,
                              void* d_out, int out_size, void* d_ws, size_t ws_size,
                              hipStream_t stream){
    const int C = 192, GH = 256, FH = 512;
    const float* x    = (const float*)d_in[0];
    const int*   ei   = (const int*)d_in[1];
    const float* Wg1  = (const float*)d_in[2];
    const float* bg1  = (const float*)d_in[3];
    const float* gg1  = (const float*)d_in[4];
    const float* beg1 = (const float*)d_in[5];
    const float* Wrel = (const float*)d_in[6];
    const float* brel = (const float*)d_in[7];
    const float* Wroot= (const float*)d_in[8];
    const float* Wg2  = (const float*)d_in[9];
    const float* bg2  = (const float*)d_in[10];
    const float* gg2  = (const float*)d_in[11];
    const float* beg2 = (const float*)d_in[12];
    const float* Wf1  = (const float*)d_in[13];
    const float* bf1  = (const float*)d_in[14];
    const float* gf1  = (const float*)d_in[15];
    const float* bef1 = (const float*)d_in[16];
    const float* Wf2  = (const float*)d_in[17];
    const float* bf2  = (const float*)d_in[18];
    const float* gf2  = (const float*)d_in[19];
    const float* bef2 = (const float*)d_in[20];

    const int N = in_sizes[0] / C;
    const int E = in_sizes[1] / 2;
    const int* e_src = ei;
    const int* e_dst = ei + E;

    // ---- workspace arena (~214 MB). Big A-source buffers placed BEFORE the
    // int buffers so gemm3's ≤130 KB staging over-read stays in-arena. ----
    char* wp = (char*)d_ws;
    auto carve = [&](size_t bytes) -> void* {
        void* p = (void*)wp; wp += (bytes + 255) & ~(size_t)255; return p;
    };
    unsigned short* wt_g1 = (unsigned short*)carve((size_t)GH * C * 2);     // [256][192]
    unsigned short* wt_rr = (unsigned short*)carve((size_t)GH * 512 * 2);   // [256][512] = [Wrel^T|Wroot^T]
    unsigned short* wt_g2 = (unsigned short*)carve((size_t)C * GH * 2);     // [192][256]
    unsigned short* wt_f1 = (unsigned short*)carve((size_t)FH * C * 2);     // [512][192]
    unsigned short* wt_f2 = (unsigned short*)carve((size_t)C * FH * 2);     // [192][512]
    float* stats = (float*)carve(2 * (size_t)(GH + C + FH + C) * 4);
    float* sum1 = stats;        float* sq1 = sum1 + GH;
    float* sum2 = sq1 + GH;     float* sq2 = sum2 + C;
    float* sum3 = sq2 + C;      float* sq3 = sum3 + FH;
    float* sum4 = sq3 + FH;     float* sq4 = sum4 + C;
    // buf0 [N,512]: pairs (CSR build, dies before h1) -> h1[N,256] -> g[N,256] -> f1/g2[N,512]
    unsigned short* buf0  = (unsigned short*)carve((size_t)N * 512 * 2);
    // bufAG [N,512]: x_bf[N,192] (dies at g1) -> AG=[agg|hbn] -> h2/x2[N,192]@0, h4[N,192]@N*192
    unsigned short* bufAG = (unsigned short*)carve((size_t)N * 512 * 2);
    int* offsets = (int*)carve((size_t)(N + 1) * 4);
    int* esrc    = (int*)carve((size_t)E * 4);
    int* bcnt    = (int*)carve((size_t)256 * 16 * 4);   // padded: 1 counter / 64B line
    int* bbase   = (int*)carve((size_t)257 * 4);
    int* bcur    = (int*)carve((size_t)256 * 16 * 4);   // padded
    unsigned short* x_bf = bufAG;                       // [N,192] overlay, dead before AG written
    int2* pairs = (int2*)buf0;                          // [E] overlay, dead before h1 written
    unsigned short* h1  = buf0;
    unsigned short* g   = buf0;
    unsigned short* f1  = buf0;                          // also g2 (in-place BN)
    unsigned short* AG  = bufAG;
    unsigned short* h2  = bufAG;                         // also x2 (in-place BN+res)
    unsigned short* h4  = bufAG + (size_t)N * C;
    (void)ws_size; (void)n_in; (void)out_size;

    const float invN = 1.0f / (float)N;
    const int GB = (N + 127) / 128;   // gemm3 grid.x
    const int nbuk = (N + RB - 1) >> RBSH;   // <=256 for N<=131072

    // weight prep
    wprep_k<<<(C * GH + 255) / 256, 256, 0, stream>>>(Wg1, wt_g1, C, GH, C, 0);
    wprep_k<<<(GH * GH + 255) / 256, 256, 0, stream>>>(Wrel, wt_rr, GH, GH, 512, 0);
    wprep_k<<<(GH * GH + 255) / 256, 256, 0, stream>>>(Wroot, wt_rr, GH, GH, 512, GH);
    wprep_k<<<(GH * C + 255) / 256, 256, 0, stream>>>(Wg2, wt_g2, GH, C, GH, 0);
    wprep_k<<<(C * FH + 255) / 256, 256, 0, stream>>>(Wf1, wt_f1, C, FH, C, 0);
    wprep_k<<<(FH * C + 255) / 256, 256, 0, stream>>>(Wf2, wt_f2, FH, C, FH, 0);

    const int nstats = 2 * (GH + C + FH + C);
    zero_k<<<(nstats + 255) / 256, 256, 0, stream>>>((int*)stats, nstats);
    zero_k<<<(256 * 16 + 255) / 256, 256, 0, stream>>>(bcnt, 256 * 16);

    // bucketed CSR build
    bhist_k<<<1024, 256, 0, stream>>>(e_dst, bcnt, E);
    bscan_k<<<1, 256, 0, stream>>>(bcnt, bbase, bcur, nbuk, E);
    bpart_k<<<(E + PCH - 1) / PCH, 512, 0, stream>>>(e_src, e_dst, bcur, pairs, E);
    bbuild_k<<<nbuk, 1024, 0, stream>>>(pairs, bbase, offsets, esrc, N, E);

    // x -> bf16 (for g1 GEMM A-input)
    xcast_k<<<(int)(((size_t)N * C / 8 + 255) / 256), 256, 0, stream>>>(x, x_bf, (long)N * C / 8);

    // ---- Grapher ----
    // h1 = x @ Wg1 + bg1
    gemm3_k<192, false><<<dim3(GB, GH / 64), 256, 0, stream>>>(x_bf, wt_g1, bg1, h1, N, GH);
    colstats_k<256><<<512, 256, 0, stream>>>(h1, sum1, sq1, N);
    // hbn = BN(h1) -> AG[:,256:512]   (x_bf dies here)
    bn_apply_k<256, false, false, false, false><<<(int)(((size_t)N * GH / 8 + 255) / 256), 256, 0, stream>>>(
        h1, AG, nullptr, sum1, sq1, gg1, beg1, N, 512, 256, invN);
    // agg -> AG[:,0:256]
    agg_k<<<(N + 3) / 4, 256, 0, stream>>>(AG + 256, offsets, esrc, AG, N);
    // g = gelu([agg|hbn] @ [Wrel;Wroot] + brel)
    gemm3_k<512, true><<<dim3(GB, GH / 64), 256, 0, stream>>>(AG, wt_rr, brel, g, N, GH);
    // h2 = g @ Wg2 + bg2
    gemm3_k<256, false><<<dim3(GB, C / 64), 256, 0, stream>>>(g, wt_g2, bg2, h2, N, C);
    colstats_k<192><<<512, 192, 0, stream>>>(h2, sum2, sq2, N);
    // x2 = BN(h2) + x   (in-place)
    bn_apply_k<192, false, true, true, false><<<(int)(((size_t)N * C / 8 + 255) / 256), 256, 0, stream>>>(
        h2, h2, x, sum2, sq2, gg2, beg2, N, 192, 0, invN);

    // ---- FFN ----
    // f1 = x2 @ Wf1 + bf1
    gemm3_k<192, false><<<dim3(GB, FH / 64), 256, 0, stream>>>(h2, wt_f1, bf1, f1, N, FH);
    colstats_k<512><<<512, 256, 0, stream>>>(f1, sum3, sq3, N);
    // g2 = gelu(BN(f1))  (in-place)
    bn_apply_k<512, true, false, false, false><<<(int)(((size_t)N * FH / 8 + 255) / 256), 256, 0, stream>>>(
        f1, f1, nullptr, sum3, sq3, gf1, bef1, N, 512, 0, invN);
    // h4 = g2 @ Wf2 + bf2
    gemm3_k<512, false><<<dim3(GB, C / 64), 256, 0, stream>>>(f1, wt_f2, bf2, h4, N, C);
    colstats_k<192><<<512, 192, 0, stream>>>(h4, sum4, sq4, N);
    // out = BN(h4) + x2  (fp32 out)
    bn_apply_k<192, false, true, false, true><<<(int)(((size_t)N * C / 8 + 255) / 256), 256, 0, stream>>>(
        h4, d_out, h2, sum4, sq4, gf2, bef2, N, 192, 0, invN);
}